// Round 1
// baseline (74.901 us; speedup 1.0000x reference)
//
#include <hip/hip_runtime.h>

// ConvDeepSet: B=8, N_IN=1024, N_OUT=4096, OUT_CHANNELS=64
//
// dens[b,m] = sum_n exp(k0*d(n,m)), conv[b,m] = sum_n y[n] exp(k1*d(n,m))
// out[b,m,o] = dens*W[o,0] + (conv/(dens+1e-8))*W[o,1] + b[o]
//
// R8: spatial culling. With sigma=log(1/32), arg_log2 = -738*d; the f32
// reference underflows to exactly 0 for arg_log2 < -149 (denormals below
// -126 sum to <=1e-35, irrelevant vs tol 0.03125 and the 1e-8 guard).
// Only ~4% of the 33.5M pairs contribute. So:
//   kernel 1: bin 4096 targets/batch into 8x8 snake-ordered cells
//             (sorted order => each block's 128 targets are spatially local)
//   kernel 2: per block, bbox(128 targets) + margin sqrt(150/|k0|) (runtime-
//             derived => exact fallback for any sigma), ballot-compact the
//             1024 source records in LDS, run the M=2 packed exp loop over
//             K~=150-250 compacted sources instead of 1024 (~5-6x less issue).
// Inner loop body unchanged from R7 (validated issue model): per 2 pairs =
// 5 pk (v_pk_add/fma) + 2 v_exp_f32; fast path r = k1/k0 == 1.

#define OUTC 64
#define MB   128
#define NW   16

typedef __attribute__((ext_vector_type(2))) float f32x2;

// ---------------------------------------------------------------------------
// Kernel 1: bin targets into 8x8 cells (snake order), one block per batch.
__global__ __launch_bounds__(1024) void bin_targets(
    const float* __restrict__ t,     // [B,4096,2]
    int* __restrict__ torder)        // [B,4096]
{
    const int b   = blockIdx.x;
    const int tid = threadIdx.x;
    __shared__ int hist[64];
    __shared__ int base[64];
    if (tid < 64) hist[tid] = 0;
    __syncthreads();

    int cid[4];
    #pragma unroll
    for (int k = 0; k < 4; ++k) {
        const int m = tid + k * 1024;
        const float2 tv = ((const float2*)(t + (size_t)b * 8192))[m];
        int cx = (int)((tv.x + 2.0f) * 2.0f); cx = min(max(cx, 0), 7);
        int cy = (int)((tv.y + 2.0f) * 2.0f); cy = min(max(cy, 0), 7);
        // snake order: consecutive cells are always spatially adjacent, so a
        // 128-target tile crossing a cell-row boundary stays compact.
        const int c = cy * 8 + ((cy & 1) ? (7 - cx) : cx);
        cid[k] = c;
        atomicAdd(&hist[c], 1);
    }
    __syncthreads();

    if (tid < 64) {                      // wave 0: exclusive scan of 64 bins
        const int v = hist[tid];
        int inc = v;
        #pragma unroll
        for (int off = 1; off < 64; off <<= 1) {
            const int u = __shfl_up(inc, off);
            if (tid >= off) inc += u;
        }
        base[tid] = inc - v;
    }
    __syncthreads();

    #pragma unroll
    for (int k = 0; k < 4; ++k) {
        const int m = tid + k * 1024;
        const int pos = atomicAdd(&base[cid[k]], 1);
        torder[(size_t)b * 4096 + pos] = m;
    }
}

// ---------------------------------------------------------------------------
// Kernel 2: main compute over sorted target tiles with source compaction.
__global__ __launch_bounds__(1024, 4) void convdeepset_kernel(
    const float* __restrict__ x,     // [B,1024,2]
    const float* __restrict__ y,     // [B,1024]
    const float* __restrict__ t,     // [B,4096,2]
    const float* __restrict__ sigma, // [2]
    const float* __restrict__ W,     // [64,2]
    const float* __restrict__ bias,  // [64]
    const int* __restrict__ torder,  // [B,4096] cell-sorted target indices
    float* __restrict__ out)         // [B,4096,64]
{
    __shared__ float4 cs[1024];          // 16 KB compacted source records
    __shared__ float  dens_part[NW*MB];  // 8 KB
    __shared__ float  conv_part[NW*MB];  // 8 KB
    __shared__ float  sums[2*MB];
    __shared__ float  dens_tot[MB];
    __shared__ float  ratio[MB];
    __shared__ float2 stt[MB];           // scaled target coords
    __shared__ int    tor[MB];           // original target indices
    __shared__ int    wcnt[NW];

    const int tid  = threadIdx.x;
    const int b    = blockIdx.x >> 5;        // 32 m-tiles per batch
    const int m0   = (blockIdx.x & 31) * MB;
    const int wave = tid >> 6;
    const int lane = tid & 63;

    const float log2e = 1.44269504088896340736f;
    const float k0 = -0.5f * __expf(-2.0f * sigma[0]) * log2e;
    const float k1 = -0.5f * __expf(-2.0f * sigma[1]) * log2e;
    const float s0 = sqrtf(-k0);
    const float r  = k1 / k0;                // conv exponent = r * arg
    // Keep source iff scaled d^2 <= 150/min(r,1): beyond that BOTH channels'
    // f32 exps are below the smallest denormal -> exact zero in the reference.
    const float marg = sqrtf(150.0f / fminf(r, 1.0f));

    // Stage own source record in registers (coalesced float2 + float).
    float sx, sy;
    float4 myrec;
    {
        const float2 xv = ((const float2*)(x + (size_t)b * 2048))[tid];
        const float  yv = y[(size_t)b * 1024 + tid];
        sx = xv.x * s0; sy = xv.y * s0;
        myrec = make_float4(sx + sx, sy + sy, -fmaf(sx, sx, sy * sy), yv);
    }

    // Load this tile's sorted target indices + scaled coords.
    if (tid < MB) {
        const int im = torder[(size_t)b * 4096 + m0 + tid];
        tor[tid] = im;
        const float2 tv = ((const float2*)(t + (size_t)b * 8192))[im];
        stt[tid] = make_float2(tv.x * s0, tv.y * s0);
    }
    __syncthreads();

    // Per-wave (redundant across waves) bbox of the tile's 128 targets.
    const float2 ta = stt[lane];
    const float2 tb = stt[64 + lane];
    float mnx = fminf(ta.x, tb.x), mxx = fmaxf(ta.x, tb.x);
    float mny = fminf(ta.y, tb.y), mxy = fmaxf(ta.y, tb.y);
    #pragma unroll
    for (int off = 32; off; off >>= 1) {
        mnx = fminf(mnx, __shfl_xor(mnx, off));
        mxx = fmaxf(mxx, __shfl_xor(mxx, off));
        mny = fminf(mny, __shfl_xor(mny, off));
        mxy = fmaxf(mxy, __shfl_xor(mxy, off));
    }
    mnx -= marg; mxx += marg; mny -= marg; mxy += marg;

    // Deterministic ballot+prefix compaction of in-range sources into cs[].
    const bool keep = (sx >= mnx) && (sx <= mxx) && (sy >= mny) && (sy <= mxy);
    const unsigned long long bal = __ballot(keep);
    if (lane == 0) wcnt[wave] = __popcll(bal);
    __syncthreads();
    int basew = 0, K = 0;
    #pragma unroll
    for (int w2 = 0; w2 < NW; ++w2) {
        const int c = wcnt[w2];
        K += c;
        if (w2 < wave) basew += c;
    }
    if (keep)
        cs[basew + __popcll(bal & ((1ull << lane) - 1ull))] = myrec;
    __syncthreads();

    // Per-lane target params (M=2: targets lane and lane+64).
    f32x2 u2, v2, cm2;
    u2.x = ta.x;  u2.y = tb.x;
    v2.x = ta.y;  v2.y = tb.y;
    cm2.x = -fmaf(ta.x, ta.x, ta.y * ta.y);
    cm2.y = -fmaf(tb.x, tb.x, tb.y * tb.y);

    f32x2 dacc = {0.f, 0.f}, cacc = {0.f, 0.f};

    if (r == 1.0f) {
        #pragma unroll 2
        for (int i = wave; i < K; i += NW) {
            const float4 p = cs[i];          // wave-broadcast b128
            f32x2 arg = cm2 + p.z;                                // pk_add
            arg = __builtin_elementwise_fma((f32x2)p.x, u2, arg);  // pk_fma
            arg = __builtin_elementwise_fma((f32x2)p.y, v2, arg);  // pk_fma
            f32x2 e;
            e.x = __builtin_amdgcn_exp2f(arg.x);
            e.y = __builtin_amdgcn_exp2f(arg.y);
            dacc += e;                                             // pk_add
            cacc = __builtin_elementwise_fma((f32x2)p.w, e, cacc); // pk_fma
        }
    } else {
        #pragma unroll 2
        for (int i = wave; i < K; i += NW) {
            const float4 p = cs[i];
            f32x2 arg = cm2 + p.z;
            arg = __builtin_elementwise_fma((f32x2)p.x, u2, arg);
            arg = __builtin_elementwise_fma((f32x2)p.y, v2, arg);
            f32x2 e, er;
            e.x  = __builtin_amdgcn_exp2f(arg.x);
            e.y  = __builtin_amdgcn_exp2f(arg.y);
            er.x = __builtin_amdgcn_exp2f(arg.x * r);
            er.y = __builtin_amdgcn_exp2f(arg.y * r);
            dacc += e;
            cacc = __builtin_elementwise_fma((f32x2)p.w, er, cacc);
        }
    }

    dens_part[wave * MB + lane]      = dacc.x;
    dens_part[wave * MB + 64 + lane] = dacc.y;
    conv_part[wave * MB + lane]      = cacc.x;
    conv_part[wave * MB + 64 + lane] = cacc.y;
    __syncthreads();

    // Cross-wave reduce: 256 threads, one (channel, m) each, 16 partials.
    if (tid < 2 * MB) {
        const int m = tid & (MB - 1);
        const float* src = (tid < MB) ? dens_part : conv_part;
        float s = 0.f;
        #pragma unroll
        for (int w = 0; w < NW; ++w) s += src[w * MB + m];
        sums[tid] = s;
    }
    __syncthreads();
    if (tid < MB) {
        const float dt = sums[tid];
        dens_tot[tid] = dt;
        ratio[tid]    = sums[MB + tid] / (dt + 1e-8f);
    }
    __syncthreads();

    // Epilogue: 128 m x 64 o; lane->o (coalesced 256B rows), rows scattered
    // by original target index.
    const int o = tid & 63;
    const int g = tid >> 6;
    const float w0 = W[o * 2 + 0];
    const float w1 = W[o * 2 + 1];
    const float bo = bias[o];
    float* outb = out + (size_t)b * 4096 * OUTC;
    #pragma unroll
    for (int i = 0; i < 8; ++i) {
        const int mm = g * 8 + i;
        outb[(size_t)tor[mm] * OUTC + o] =
            fmaf(dens_tot[mm], w0, fmaf(ratio[mm], w1, bo));
    }
}

extern "C" void kernel_launch(void* const* d_in, const int* in_sizes, int n_in,
                              void* d_out, int out_size, void* d_ws, size_t ws_size,
                              hipStream_t stream) {
    const float* x     = (const float*)d_in[0];
    const float* y     = (const float*)d_in[1];
    const float* t     = (const float*)d_in[2];
    const float* sigma = (const float*)d_in[3];
    const float* W     = (const float*)d_in[4];
    const float* bias  = (const float*)d_in[5];
    float* out = (float*)d_out;
    int* torder = (int*)d_ws;            // 8*4096*4 = 128 KB of workspace

    bin_targets<<<dim3(8), dim3(1024), 0, stream>>>(t, torder);
    convdeepset_kernel<<<dim3(256), dim3(1024), 0, stream>>>(
        x, y, t, sigma, W, bias, torder, out);
}

// Round 2
// 71.653 us; speedup vs baseline: 1.0453x; 1.0453x over previous
//
#include <hip/hip_runtime.h>

// ConvDeepSet: B=8, N_IN=1024, N_OUT=4096, OUT_CHANNELS=64
//
// dens[b,m] = sum_n exp(k0*d(n,m)), conv[b,m] = sum_n y[n] exp(k1*d(n,m))
// out[b,m,o] = dens*W[o,0] + (conv/(dens+1e-8))*W[o,1] + b[o]
//
// R9: block-granularity restructure. R8 proved the pair loop is NOT the
// bottleneck (6x cull -> no change; issue model: whole loop ~2.8us chip-wide).
// Remaining suspects: per-block structural overhead at 1 block/CU (no
// co-resident block to hide startup/barrier/tail stalls; 100% tail on any
// dispatch imbalance). Fix: 1024 blocks x 256 thr (4 waves), MB=32 targets
// per block, ~25KB LDS -> 4-6 blocks/CU co-resident.
//   - M=2 packed f32x2 loop unchanged (5 pk + 2 exp per 2 pairs, r==1 fast
//     path); each lane covers m=ml and ml+16 (ml=lane&15).
//   - quarter-wave n-split: quarter q takes n = w*256 + 4*i + q; the 4
//     distinct broadcast b128 reads/wave hit banks {4q..4q+3}+16i -> disjoint.
//   - partial rows padded to MB+1=33 words -> conflict-free partial writes.
//   - 3 barriers total (was 4); reduce fused into one 32-thread pass.

#define OUTC 64
#define MB   32
#define NROW 16   // 4 waves x 4 quarters

typedef __attribute__((ext_vector_type(2))) float f32x2;

__global__ __launch_bounds__(256, 4) void convdeepset_kernel(
    const float* __restrict__ x,     // [B,1024,2]
    const float* __restrict__ y,     // [B,1024]
    const float* __restrict__ t,     // [B,4096,2]
    const float* __restrict__ sigma, // [2]
    const float* __restrict__ W,     // [64,2]
    const float* __restrict__ bias,  // [64]
    float* __restrict__ out)         // [B,4096,64]
{
    __shared__ float4 pk[1024];              // 16 KB: (2sx, 2sy, q, y)
    __shared__ float  dens_part[NROW*(MB+1)]; // padded rows: no bank conflict
    __shared__ float  conv_part[NROW*(MB+1)];
    __shared__ float  dens_tot[MB];
    __shared__ float  ratio[MB];

    const int tid = threadIdx.x;
    const int b   = blockIdx.x >> 7;          // 128 m-tiles per batch
    const int m0  = (blockIdx.x & 127) * MB;

    const float log2e = 1.44269504088896340736f;
    const float k0 = -0.5f * __expf(-2.0f * sigma[0]) * log2e;
    const float k1 = -0.5f * __expf(-2.0f * sigma[1]) * log2e;
    const float s0 = sqrtf(-k0);
    const float r  = k1 / k0;                 // conv exponent = r * arg

    // Stage all 1024 source records, 4 per thread, coalesced.
    #pragma unroll
    for (int k = 0; k < 4; ++k) {
        const int i = tid + k * 256;
        const float2 xv = ((const float2*)(x + (size_t)b * 2048))[i];
        const float  yv = y[(size_t)b * 1024 + i];
        const float sx = xv.x * s0, sy = xv.y * s0;
        pk[i] = make_float4(sx + sx, sy + sy, -fmaf(sx, sx, sy * sy), yv);
    }

    const int wave = tid >> 6;
    const int lane = tid & 63;
    const int q    = lane >> 4;               // quarter-wave: n-subset
    const int ml   = lane & 15;               // m = m0+ml and m0+ml+16

    // Per-lane target params (M=2).
    const float2* tg = (const float2*)(t + ((size_t)b * 4096 + m0) * 2);
    const float2 ta = tg[ml];
    const float2 tb = tg[16 + ml];
    f32x2 u2, v2, cm2;
    u2.x = ta.x * s0;  u2.y = tb.x * s0;
    v2.x = ta.y * s0;  v2.y = tb.y * s0;
    cm2.x = -fmaf(u2.x, u2.x, v2.x * v2.x);
    cm2.y = -fmaf(u2.y, u2.y, v2.y * v2.y);

    __syncthreads();

    f32x2 dacc = {0.f, 0.f}, cacc = {0.f, 0.f};
    const int nbase = wave * 256 + q;         // n = nbase + 4*i, i=0..63

    if (r == 1.0f) {
        #pragma unroll 4
        for (int i = 0; i < 64; ++i) {
            const float4 p = pk[nbase + i * 4];   // quarter-broadcast b128
            f32x2 arg = cm2 + p.z;                                 // pk_add
            arg = __builtin_elementwise_fma((f32x2)p.x, u2, arg);  // pk_fma
            arg = __builtin_elementwise_fma((f32x2)p.y, v2, arg);  // pk_fma
            f32x2 e;
            e.x = __builtin_amdgcn_exp2f(arg.x);
            e.y = __builtin_amdgcn_exp2f(arg.y);
            dacc += e;                                             // pk_add
            cacc = __builtin_elementwise_fma((f32x2)p.w, e, cacc); // pk_fma
        }
    } else {
        #pragma unroll 2
        for (int i = 0; i < 64; ++i) {
            const float4 p = pk[nbase + i * 4];
            f32x2 arg = cm2 + p.z;
            arg = __builtin_elementwise_fma((f32x2)p.x, u2, arg);
            arg = __builtin_elementwise_fma((f32x2)p.y, v2, arg);
            f32x2 e, er;
            e.x  = __builtin_amdgcn_exp2f(arg.x);
            e.y  = __builtin_amdgcn_exp2f(arg.y);
            er.x = __builtin_amdgcn_exp2f(arg.x * r);
            er.y = __builtin_amdgcn_exp2f(arg.y * r);
            dacc += e;
            cacc = __builtin_elementwise_fma((f32x2)p.w, er, cacc);
        }
    }

    const int row = (wave << 2) | q;          // 16 partial rows
    dens_part[row * (MB + 1) + ml]      = dacc.x;
    dens_part[row * (MB + 1) + 16 + ml] = dacc.y;
    conv_part[row * (MB + 1) + ml]      = cacc.x;
    conv_part[row * (MB + 1) + 16 + ml] = cacc.y;
    __syncthreads();

    // Fused reduce: 32 threads, both channels, ratio in the same pass.
    if (tid < MB) {
        float sd = 0.f, sc = 0.f;
        #pragma unroll
        for (int w = 0; w < NROW; ++w) {
            sd += dens_part[w * (MB + 1) + tid];
            sc += conv_part[w * (MB + 1) + tid];
        }
        dens_tot[tid] = sd;
        ratio[tid]    = sc / (sd + 1e-8f);
    }
    __syncthreads();

    // Epilogue: 32 m x 64 o; lane->o (coalesced 256B rows), 4 groups x 8 m.
    const int o = tid & 63;
    const int g = tid >> 6;
    const float w0 = W[o * 2 + 0];
    const float w1 = W[o * 2 + 1];
    const float bo = bias[o];
    float* outb = out + ((size_t)b * 4096 + m0) * OUTC;
    #pragma unroll
    for (int i = 0; i < 8; ++i) {
        const int mm = g * 8 + i;
        outb[mm * OUTC + o] = fmaf(dens_tot[mm], w0, fmaf(ratio[mm], w1, bo));
    }
}

extern "C" void kernel_launch(void* const* d_in, const int* in_sizes, int n_in,
                              void* d_out, int out_size, void* d_ws, size_t ws_size,
                              hipStream_t stream) {
    const float* x     = (const float*)d_in[0];
    const float* y     = (const float*)d_in[1];
    const float* t     = (const float*)d_in[2];
    const float* sigma = (const float*)d_in[3];
    const float* W     = (const float*)d_in[4];
    const float* bias  = (const float*)d_in[5];
    float* out = (float*)d_out;

    // 8 batches x 128 m-tiles = 1024 blocks x 256 thr: 4-6 blocks/CU
    // co-resident (25KB LDS each) so startup/barrier/tail stalls overlap.
    convdeepset_kernel<<<dim3(1024), dim3(256), 0, stream>>>(
        x, y, t, sigma, W, bias, out);
}